// Round 1
// baseline (250.292 us; speedup 1.0000x reference)
//
#include <hip/hip_runtime.h>

#define KDIM 768
#define MANS 640      // L*B*T
#define VV   30000
#define NGRP 235      // ceil(30000/128)
#define NKS  (KDIM / 64)   // 12 k-steps

typedef __attribute__((ext_vector_type(4)))  float  f32x4;
typedef __attribute__((ext_vector_type(16))) float  f32x16;
typedef __attribute__((ext_vector_type(8)))  __bf16 bf16x8;
typedef __attribute__((ext_vector_type(8)))  unsigned short ushort8;

__device__ __forceinline__ unsigned short f2bf(float f) {
    union { float f; unsigned int u; } v; v.f = f;
    unsigned int r = v.u + 0x7fffu + ((v.u >> 16) & 1u);  // RNE
    return (unsigned short)(r >> 16);
}

__device__ __forceinline__ ushort8 cvt8(f32x4 a, f32x4 b) {
    ushort8 o;
    o[0] = f2bf(a.x); o[1] = f2bf(a.y); o[2] = f2bf(a.z); o[3] = f2bf(a.w);
    o[4] = f2bf(b.x); o[5] = f2bf(b.y); o[6] = f2bf(b.z); o[7] = f2bf(b.w);
    return o;
}

__device__ __forceinline__ void load_lds16(const unsigned short* g, unsigned short* l) {
    __builtin_amdgcn_global_load_lds(
        (__attribute__((address_space(1))) void*)(void*)g,
        (__attribute__((address_space(3))) void*)l,
        16, 0, 0);
}

// ===================== prep_small (unchanged) =====================
// blocks [0,144):   W[768][768] f32 -> Wt[k][d]=W[d][k] bf16 (64x64 tiles)
// blocks [144,304): c[m] = dot(answer[m], b)
__global__ __launch_bounds__(256) void prep_small(
    const float* __restrict__ W, const float* __restrict__ A,
    const float* __restrict__ b, unsigned short* __restrict__ Wt_bf,
    float* __restrict__ cvec)
{
    __shared__ float ts[64][65];
    const int blk = blockIdx.x;
    if (blk < 144) {
        int bx = (blk % 12) * 64, by = (blk / 12) * 64;
        int tx = threadIdx.x & 63, tg = threadIdx.x >> 6;
#pragma unroll
        for (int i = 0; i < 16; ++i) {
            int r = tg * 16 + i;
            ts[r][tx] = W[(long)(by + r) * KDIM + bx + tx];
        }
        __syncthreads();
#pragma unroll
        for (int i = 0; i < 16; ++i) {
            int r = tg * 16 + i;
            Wt_bf[(long)(bx + r) * KDIM + by + tx] = f2bf(ts[tx][r]);
        }
    } else {
        int row  = (blk - 144) * 4 + (threadIdx.x >> 6);
        int lane = threadIdx.x & 63;
        const float* ap = A + (long)row * KDIM;
        float s = 0.f;
#pragma unroll
        for (int i = 0; i < KDIM / 64; ++i) s += ap[i * 64 + lane] * b[i * 64 + lane];
#pragma unroll
        for (int off = 32; off; off >>= 1) s += __shfl_down(s, off, 64);
        if (lane == 0) cvec[row] = s;
    }
}

// ===================== a2 gemm: 64x128 tile, 2-phase double-buffered =====================
// A2[m][k] = sum_d answer[m][d] * Wt[k][d], bf16 out.
// A (answer f32) reg-staged w/ issue-early/write-late; B (Wt bf16) via DMA.
__global__ __launch_bounds__(256) void gemm_a2(
    const float* __restrict__ Af, const unsigned short* __restrict__ Bp,
    unsigned short* __restrict__ outp)
{
    constexpr int TM = 64, TN = 128;
    __shared__ unsigned short sA[2][TM * 64];   // 2 x 8 KB
    __shared__ unsigned short sB[2][TN * 64];   // 2 x 16 KB

    const int t    = threadIdx.x;
    const int lane = t & 63;
    const int w    = t >> 6;
    const int wm   = w >> 1;
    const int wn   = w & 1;
    const int half = lane >> 5;
    const int col  = lane & 31;
    const long m0  = (long)blockIdx.x * TM;
    const long n0  = (long)blockIdx.y * TN;

    f32x16 acc[2];
    acc[0] = (f32x16)(0.f);
    acc[1] = (f32x16)(0.f);

    // A reg-stage addressing: 512 16B chunks, 2 per thread
    const float* gaf[2]; int laOff[2];
#pragma unroll
    for (int j = 0; j < 2; ++j) {
        int s   = (j * 4 + w) * 64 + lane;
        int row = s >> 3;
        int c   = (s & 7) ^ (row & 7);
        gaf[j]  = Af + (m0 + row) * KDIM + c * 8;
        laOff[j] = s * 8;
    }
    // B DMA addressing: 1024 chunks, source XOR-swizzled, dest wave-uniform
    const unsigned short* gb[4]; unsigned short* lbB[4];
#pragma unroll
    for (int j = 0; j < 4; ++j) {
        int s   = (j * 4 + w) * 64 + lane;
        int row = s >> 3;
        int c   = (s & 7) ^ (row & 7);
        gb[j]  = Bp + (n0 + row) * KDIM + c * 8;
        lbB[j] = &sB[0][(j * 4 + w) * 64 * 8];
    }

    auto compute = [&](int pp) {
        const unsigned short* bA = &sA[0][0] + pp * (TM * 64);
        const unsigned short* bB = &sB[0][0] + pp * (TN * 64);
#pragma unroll
        for (int g = 0; g < 4; ++g) {
            const int cg = g * 2 + half;
            int arow = wm * 32 + col;
            bf16x8 af = *(const bf16x8*)&bA[(arow * 8 + (cg ^ (arow & 7))) * 8];
#pragma unroll
            for (int fn = 0; fn < 2; ++fn) {
                int brow = wn * 64 + fn * 32 + col;
                bf16x8 bfv = *(const bf16x8*)&bB[(brow * 8 + (cg ^ (brow & 7))) * 8];
                acc[fn] = __builtin_amdgcn_mfma_f32_32x32x16_bf16(
                    af, bfv, acc[fn], 0, 0, 0);
            }
        }
    };

    // ---- prologue: tile 0 -> buf 0
#pragma unroll
    for (int j = 0; j < 4; ++j) load_lds16(gb[j], lbB[j]);
    {
        f32x4 ra[4];
#pragma unroll
        for (int j = 0; j < 2; ++j) {
            ra[2 * j]     = ((const f32x4*)gaf[j])[0];
            ra[2 * j + 1] = ((const f32x4*)gaf[j])[1];
        }
#pragma unroll
        for (int j = 0; j < 2; ++j)
            *(ushort8*)(&sA[0][0] + laOff[j]) = cvt8(ra[2 * j], ra[2 * j + 1]);
    }
    __syncthreads();

    int p = 0;
    for (int kt = 0; kt < NKS - 1; ++kt) {
        const int kn = (kt + 1) * 64;
        const int oB = (p ^ 1) * (TN * 64);
        const int oA = (p ^ 1) * (TM * 64);
        // issue next-tile loads EARLY
#pragma unroll
        for (int j = 0; j < 4; ++j) load_lds16(gb[j] + kn, lbB[j] + oB);
        f32x4 ra[4];
#pragma unroll
        for (int j = 0; j < 2; ++j) {
            ra[2 * j]     = ((const f32x4*)(gaf[j] + kn))[0];
            ra[2 * j + 1] = ((const f32x4*)(gaf[j] + kn))[1];
        }
        // compute current tile (hides load latency)
        compute(p);
        // write staged A LATE
#pragma unroll
        for (int j = 0; j < 2; ++j)
            *(ushort8*)(&sA[0][0] + oA + laOff[j]) = cvt8(ra[2 * j], ra[2 * j + 1]);
        __syncthreads();
        p ^= 1;
    }
    compute(p);

#pragma unroll
    for (int fn = 0; fn < 2; ++fn) {
        long n = n0 + wn * 64 + fn * 32 + col;
#pragma unroll
        for (int rg = 0; rg < 16; ++rg) {
            long m = m0 + wm * 32 + (rg & 3) + 8 * (rg >> 2) + 4 * half;
            outp[m * KDIM + n] = f2bf(acc[fn][rg]);
        }
    }
}

// ===================== big gemm: out = A2 @ vocab^T + c =====================
// 128x128 tile, BK=64, 2-phase double-buffered (T3-minimum + T14).
// A = A2 bf16 via DMA; B = vocab f32 reg-staged, cvt+ds_write after MFMA.
// XCD-grouping: id%8 = XCD; 5 m-blocks of one n-group share an XCD.
__global__ __launch_bounds__(256) void gemm_big(
    const unsigned short* __restrict__ A, const float* __restrict__ Bf,
    const float* __restrict__ cvec, float* __restrict__ outp)
{
    const int id    = blockIdx.x;
    const int x     = id & 7;
    const int q     = id >> 3;
    const int m_idx = q % 5;
    const int n_grp = (q / 5) * 8 + x;
    if (n_grp >= NGRP) return;               // 25 pad blocks idle

    __shared__ unsigned short sA[2][128 * 64];   // 2 x 16 KB
    __shared__ unsigned short sB[2][128 * 64];   // 2 x 16 KB

    const int t    = threadIdx.x;
    const int lane = t & 63;
    const int w    = t >> 6;
    const int wm   = w >> 1;
    const int wn   = w & 1;
    const int half = lane >> 5;
    const int col  = lane & 31;
    const long m0  = (long)m_idx * 128;
    const long n0  = (long)n_grp * 128;

    f32x16 acc[2][2];
#pragma unroll
    for (int i = 0; i < 2; ++i)
#pragma unroll
        for (int j = 0; j < 2; ++j) acc[i][j] = (f32x16)(0.f);

    // A staging: 1024 chunks via DMA, source XOR-swizzled, dest wave-uniform
    const unsigned short* ga[4];
    unsigned short*       laA[4];
#pragma unroll
    for (int j = 0; j < 4; ++j) {
        int s   = (j * 4 + w) * 64 + lane;
        int row = s >> 3;
        int c   = (s & 7) ^ (row & 7);
        ga[j]  = A + (m0 + row) * KDIM + c * 8;
        laA[j] = &sA[0][(j * 4 + w) * 64 * 8];
    }
    // B staging: 1024 chunks, reg-staged f32 -> bf16 (row clamped to 29999)
    const float* gb[4]; int lbOff[4];
#pragma unroll
    for (int j = 0; j < 4; ++j) {
        int s   = j * 256 + t;
        int row = s >> 3;
        int c   = (s & 7) ^ (row & 7);
        long grow = n0 + row;
        if (grow > VV - 1) grow = VV - 1;
        gb[j]   = Bf + grow * KDIM + c * 8;
        lbOff[j] = s * 8;
    }

    auto compute = [&](int pp) {
        const unsigned short* bA = &sA[0][0] + pp * (128 * 64);
        const unsigned short* bB = &sB[0][0] + pp * (128 * 64);
#pragma unroll
        for (int g = 0; g < 4; ++g) {
            const int cg = g * 2 + half;
            bf16x8 af[2], bfr[2];
#pragma unroll
            for (int fm = 0; fm < 2; ++fm) {
                int row = wm * 64 + fm * 32 + col;
                af[fm] = *(const bf16x8*)&bA[(row * 8 + (cg ^ (row & 7))) * 8];
            }
#pragma unroll
            for (int fn = 0; fn < 2; ++fn) {
                int row = wn * 64 + fn * 32 + col;
                bfr[fn] = *(const bf16x8*)&bB[(row * 8 + (cg ^ (row & 7))) * 8];
            }
#pragma unroll
            for (int fm = 0; fm < 2; ++fm)
#pragma unroll
                for (int fn = 0; fn < 2; ++fn)
                    acc[fm][fn] = __builtin_amdgcn_mfma_f32_32x32x16_bf16(
                        af[fm], bfr[fn], acc[fm][fn], 0, 0, 0);
        }
    };

    // ---- prologue: tile 0 -> buf 0
#pragma unroll
    for (int j = 0; j < 4; ++j) load_lds16(ga[j], laA[j]);
    {
        f32x4 rb[8];
#pragma unroll
        for (int j = 0; j < 4; ++j) {
            rb[2 * j]     = ((const f32x4*)gb[j])[0];
            rb[2 * j + 1] = ((const f32x4*)gb[j])[1];
        }
#pragma unroll
        for (int j = 0; j < 4; ++j)
            *(ushort8*)(&sB[0][0] + lbOff[j]) = cvt8(rb[2 * j], rb[2 * j + 1]);
    }
    __syncthreads();

    int p = 0;
    for (int kt = 0; kt < NKS - 1; ++kt) {
        const int kn = (kt + 1) * 64;
        const int o1 = (p ^ 1) * (128 * 64);
        // issue next-tile loads EARLY: DMA for A, regs for B
#pragma unroll
        for (int j = 0; j < 4; ++j) load_lds16(ga[j] + kn, laA[j] + o1);
        f32x4 nb[8];
#pragma unroll
        for (int j = 0; j < 4; ++j) {
            nb[2 * j]     = ((const f32x4*)(gb[j] + kn))[0];
            nb[2 * j + 1] = ((const f32x4*)(gb[j] + kn))[1];
        }
        // compute current tile — load latency hides under 16 MFMAs
        compute(p);
        // convert + write staged B LATE (T14)
#pragma unroll
        for (int j = 0; j < 4; ++j)
            *(ushort8*)(&sB[0][0] + o1 + lbOff[j]) = cvt8(nb[2 * j], nb[2 * j + 1]);
        __syncthreads();
        p ^= 1;
    }
    compute(p);

#pragma unroll
    for (int fm = 0; fm < 2; ++fm)
#pragma unroll
        for (int fn = 0; fn < 2; ++fn) {
            long n = n0 + wn * 64 + fn * 32 + col;
            if (n < VV) {
#pragma unroll
                for (int rg = 0; rg < 16; ++rg) {
                    long m = m0 + wm * 64 + fm * 32
                           + (rg & 3) + 8 * (rg >> 2) + 4 * half;
                    outp[m * (long)VV + n] = acc[fm][fn][rg] + cvec[m];
                }
            }
        }
}

extern "C" void kernel_launch(void* const* d_in, const int* in_sizes, int n_in,
                              void* d_out, int out_size, void* d_ws, size_t ws_size,
                              hipStream_t stream) {
    const float* answer = (const float*)d_in[0];   // [640][768] f32
    const float* vocab  = (const float*)d_in[1];   // [30000][768] f32
    const float* W      = (const float*)d_in[2];   // [768][768] f32
    const float* bvec   = (const float*)d_in[3];   // [768] f32

    char* ws = (char*)d_ws;
    unsigned short* Wt_bf = (unsigned short*)ws;                    // 1,179,648 B
    unsigned short* A2_bf = (unsigned short*)(ws + 1179648);        //   983,040 B
    float*          cptr  = (float*)(ws + 1179648 + 983040);        //     2,560 B

    // 1. Wt = W^T (bf16), c = answer @ b
    prep_small<<<304, 256, 0, stream>>>(W, answer, bvec, Wt_bf, cptr);

    // 2. A2[m][k] = sum_d answer[m][d] * Wt[k][d]   (60 blocks, pipelined)
    gemm_a2<<<dim3(MANS / 64, KDIM / 128), 256, 0, stream>>>(answer, Wt_bf, A2_bf);

    // 3. out[m][v] = sum_k A2[m][k] * vocab_bf16(v,k) + c[m]
    //    1200 blocks (25 idle), XCD-grouped swizzle, 2-phase pipeline.
    gemm_big<<<1200, 256, 0, stream>>>(A2_bf, vocab, cptr, (float*)d_out);
}

// Round 2
// 222.215 us; speedup vs baseline: 1.1264x; 1.1264x over previous
//
#include <hip/hip_runtime.h>

#define KDIM 768
#define MANS 640      // L*B*T
#define VV   30000
#define NGRP 235      // ceil(30000/128)
#define VELEM (VV * KDIM)                  // 23,040,000 floats in vocab
#define CVTBLK ((VELEM + 8191) / 8192)     // 2813 conversion blocks
#define A2BLK  ((MANS / 64) * (KDIM / 128))  // 60 gemm blocks

typedef __attribute__((ext_vector_type(4)))  float  f32x4;
typedef __attribute__((ext_vector_type(16))) float  f32x16;
typedef __attribute__((ext_vector_type(8)))  __bf16 bf16x8;
typedef __attribute__((ext_vector_type(8)))  unsigned short ushort8;

// native f32->bf16 (RNE via v_cvt_pk_bf16_f32; compiler packs pairs — m240)
__device__ __forceinline__ unsigned short f2bf(float f) {
    union { __bf16 h; unsigned short u; } t;
    t.h = (__bf16)f;
    return t.u;
}

__device__ __forceinline__ ushort8 cvt8(f32x4 a, f32x4 b) {
    union { bf16x8 h; ushort8 u; } c;
    c.h[0] = (__bf16)a.x; c.h[1] = (__bf16)a.y;
    c.h[2] = (__bf16)a.z; c.h[3] = (__bf16)a.w;
    c.h[4] = (__bf16)b.x; c.h[5] = (__bf16)b.y;
    c.h[6] = (__bf16)b.z; c.h[7] = (__bf16)b.w;
    return c.u;
}

__device__ __forceinline__ void load_lds16(const unsigned short* g, unsigned short* l) {
    __builtin_amdgcn_global_load_lds(
        (__attribute__((address_space(1))) void*)(void*)g,
        (__attribute__((address_space(3))) void*)l,
        16, 0, 0);
}

// ===================== prep_small =====================
// blocks [0,144):   W[768][768] f32 -> Wt[k][d]=W[d][k] bf16 (64x64 tiles)
// blocks [144,304): c[m] = dot(answer[m], b)
__global__ __launch_bounds__(256) void prep_small(
    const float* __restrict__ W, const float* __restrict__ A,
    const float* __restrict__ b, unsigned short* __restrict__ Wt_bf,
    float* __restrict__ cvec)
{
    __shared__ float ts[64][65];
    const int blk = blockIdx.x;
    if (blk < 144) {
        int bx = (blk % 12) * 64, by = (blk / 12) * 64;
        int tx = threadIdx.x & 63, tg = threadIdx.x >> 6;
#pragma unroll
        for (int i = 0; i < 16; ++i) {
            int r = tg * 16 + i;
            ts[r][tx] = W[(long)(by + r) * KDIM + bx + tx];
        }
        __syncthreads();
#pragma unroll
        for (int i = 0; i < 16; ++i) {
            int r = tg * 16 + i;
            Wt_bf[(long)(bx + r) * KDIM + by + tx] = f2bf(ts[tx][r]);
        }
    } else {
        int row  = (blk - 144) * 4 + (threadIdx.x >> 6);
        int lane = threadIdx.x & 63;
        const float* ap = A + (long)row * KDIM;
        float s = 0.f;
#pragma unroll
        for (int i = 0; i < KDIM / 64; ++i) s += ap[i * 64 + lane] * b[i * 64 + lane];
#pragma unroll
        for (int off = 32; off; off >>= 1) s += __shfl_down(s, off, 64);
        if (lane == 0) cvec[row] = s;
    }
}

// ===================== a2 gemm + vocab cvt (fused grid) =====================
// blocks [0,60):      A2[m][k] = sum_d answer[m][d] * Wt[k][d], bf16 out.
//                     (round-0 single-buffer structure — 24 KB LDS, TLP-hidden)
// blocks [60,2873):   vocab f32 -> bf16 streaming cvt on the ~196 idle CUs.
__global__ __launch_bounds__(256) void gemm_a2(
    const float* __restrict__ Af, const unsigned short* __restrict__ Bp,
    unsigned short* __restrict__ outp,
    const float* __restrict__ vocab, unsigned short* __restrict__ vocab_bf)
{
    if (blockIdx.x >= A2BLK) {
        // ---- vocab conversion: 8192 floats per block, 4 passes of t*8 ----
        const long base = (long)(blockIdx.x - A2BLK) * 8192 + (long)threadIdx.x * 8;
#pragma unroll
        for (int p = 0; p < 4; ++p) {
            long idx = base + p * 2048;
            if (idx < VELEM) {
                f32x4 v0 = ((const f32x4*)(vocab + idx))[0];
                f32x4 v1 = ((const f32x4*)(vocab + idx))[1];
                *(ushort8*)(vocab_bf + idx) = cvt8(v0, v1);
            }
        }
        return;
    }

    constexpr int TM = 64, TN = 128;
    __shared__ unsigned short sA[TM * 64];   // 8 KB
    __shared__ unsigned short sB[TN * 64];   // 16 KB

    const int t    = threadIdx.x;
    const int lane = t & 63;
    const int w    = t >> 6;
    const int wm   = w >> 1;
    const int wn   = w & 1;
    const int half = lane >> 5;
    const int col  = lane & 31;
    const long m0  = (long)(blockIdx.x % (MANS / 64)) * TM;
    const long n0  = (long)(blockIdx.x / (MANS / 64)) * TN;

    f32x16 acc[2];
    acc[0] = (f32x16)(0.f);
    acc[1] = (f32x16)(0.f);

    // A reg-stage addressing: 512 16B chunks, 2 per thread
    const float* gaf[2]; int laOff[2];
#pragma unroll
    for (int j = 0; j < 2; ++j) {
        int s   = (j * 4 + w) * 64 + lane;
        int row = s >> 3;
        int c   = (s & 7) ^ (row & 7);
        gaf[j]   = Af + (m0 + row) * KDIM + c * 8;
        laOff[j] = s * 8;
    }
    // B DMA addressing: 1024 chunks, source XOR-swizzled, dest wave-uniform
    const unsigned short* gb[4]; unsigned short* lbB[4];
#pragma unroll
    for (int j = 0; j < 4; ++j) {
        int s   = (j * 4 + w) * 64 + lane;
        int row = s >> 3;
        int c   = (s & 7) ^ (row & 7);
        gb[j]  = Bp + (n0 + row) * KDIM + c * 8;
        lbB[j] = &sB[(j * 4 + w) * 64 * 8];
    }

    for (int k0 = 0; k0 < KDIM; k0 += 64) {
#pragma unroll
        for (int j = 0; j < 4; ++j) load_lds16(gb[j] + k0, lbB[j]);
#pragma unroll
        for (int j = 0; j < 2; ++j) {
            f32x4 v0 = ((const f32x4*)(gaf[j] + k0))[0];
            f32x4 v1 = ((const f32x4*)(gaf[j] + k0))[1];
            *(ushort8*)(&sA[0] + laOff[j]) = cvt8(v0, v1);
        }
        __syncthreads();

#pragma unroll
        for (int g = 0; g < 4; ++g) {
            const int cg = g * 2 + half;
            int arow = wm * 32 + col;
            bf16x8 af = *(const bf16x8*)&sA[(arow * 8 + (cg ^ (arow & 7))) * 8];
#pragma unroll
            for (int fn = 0; fn < 2; ++fn) {
                int brow = wn * 64 + fn * 32 + col;
                bf16x8 bfv = *(const bf16x8*)&sB[(brow * 8 + (cg ^ (brow & 7))) * 8];
                acc[fn] = __builtin_amdgcn_mfma_f32_32x32x16_bf16(
                    af, bfv, acc[fn], 0, 0, 0);
            }
        }
        __syncthreads();
    }

#pragma unroll
    for (int fn = 0; fn < 2; ++fn) {
        long n = n0 + wn * 64 + fn * 32 + col;
#pragma unroll
        for (int rg = 0; rg < 16; ++rg) {
            long m = m0 + wm * 32 + (rg & 3) + 8 * (rg >> 2) + 4 * half;
            outp[m * KDIM + n] = f2bf(acc[fn][rg]);
        }
    }
}

// ===================== big gemm: out = A2 @ vocab_bf^T + c =====================
// 128x128 tile, BK=64, single-buffer 32 KB LDS (5 blocks/CU co-residency = the
// latency hiding — round-1 showed 64 KB dbuf regresses). BOTH operands bf16 via
// global_load_lds DMA: zero cvt VALU, zero reg staging in the hot loop.
// XCD-grouping: id%8 = XCD; 5 m-blocks of one n-group share an XCD.
__global__ __launch_bounds__(256) void gemm_big(
    const unsigned short* __restrict__ A, const unsigned short* __restrict__ Bbf,
    const float* __restrict__ cvec, float* __restrict__ outp)
{
    const int id    = blockIdx.x;
    const int x     = id & 7;
    const int q     = id >> 3;
    const int m_idx = q % 5;
    const int n_grp = (q / 5) * 8 + x;
    if (n_grp >= NGRP) return;               // 25 pad blocks idle

    __shared__ unsigned short sA[128 * 64];  // 16 KB
    __shared__ unsigned short sB[128 * 64];  // 16 KB

    const int t    = threadIdx.x;
    const int lane = t & 63;
    const int w    = t >> 6;
    const int wm   = w >> 1;
    const int wn   = w & 1;
    const int half = lane >> 5;
    const int col  = lane & 31;
    const long m0  = (long)m_idx * 128;
    const long n0  = (long)n_grp * 128;

    f32x16 acc[2][2];
#pragma unroll
    for (int i = 0; i < 2; ++i)
#pragma unroll
        for (int j = 0; j < 2; ++j) acc[i][j] = (f32x16)(0.f);

    // A staging: 1024 chunks via DMA, source XOR-swizzled, dest wave-uniform
    const unsigned short* ga[4];
    unsigned short*       laA[4];
#pragma unroll
    for (int j = 0; j < 4; ++j) {
        int s   = (j * 4 + w) * 64 + lane;
        int row = s >> 3;
        int c   = (s & 7) ^ (row & 7);
        ga[j]  = A + (m0 + row) * KDIM + c * 8;
        laA[j] = &sA[(j * 4 + w) * 64 * 8];
    }
    // B staging: 1024 chunks via DMA from pre-converted bf16 vocab (row clamped)
    const unsigned short* gb[4];
    unsigned short*       laB[4];
#pragma unroll
    for (int j = 0; j < 4; ++j) {
        int s   = (j * 4 + w) * 64 + lane;
        int row = s >> 3;
        int c   = (s & 7) ^ (row & 7);
        long grow = n0 + row;
        if (grow > VV - 1) grow = VV - 1;
        gb[j]  = Bbf + grow * KDIM + c * 8;
        laB[j] = &sB[(j * 4 + w) * 64 * 8];
    }

    for (int k0 = 0; k0 < KDIM; k0 += 64) {
#pragma unroll
        for (int j = 0; j < 4; ++j) load_lds16(ga[j] + k0, laA[j]);
#pragma unroll
        for (int j = 0; j < 4; ++j) load_lds16(gb[j] + k0, laB[j]);
        __syncthreads();

#pragma unroll
        for (int g = 0; g < 4; ++g) {
            const int cg = g * 2 + half;
            bf16x8 af[2], bfr[2];
#pragma unroll
            for (int fm = 0; fm < 2; ++fm) {
                int row = wm * 64 + fm * 32 + col;
                af[fm] = *(const bf16x8*)&sA[(row * 8 + (cg ^ (row & 7))) * 8];
            }
#pragma unroll
            for (int fn = 0; fn < 2; ++fn) {
                int row = wn * 64 + fn * 32 + col;
                bfr[fn] = *(const bf16x8*)&sB[(row * 8 + (cg ^ (row & 7))) * 8];
            }
#pragma unroll
            for (int fm = 0; fm < 2; ++fm)
#pragma unroll
                for (int fn = 0; fn < 2; ++fn)
                    acc[fm][fn] = __builtin_amdgcn_mfma_f32_32x32x16_bf16(
                        af[fm], bfr[fn], acc[fm][fn], 0, 0, 0);
        }
        __syncthreads();
    }

#pragma unroll
    for (int fm = 0; fm < 2; ++fm)
#pragma unroll
        for (int fn = 0; fn < 2; ++fn) {
            long n = n0 + wn * 64 + fn * 32 + col;
            if (n < VV) {
#pragma unroll
                for (int rg = 0; rg < 16; ++rg) {
                    long m = m0 + wm * 64 + fm * 32
                           + (rg & 3) + 8 * (rg >> 2) + 4 * half;
                    outp[m * (long)VV + n] = acc[fm][fn][rg] + cvec[m];
                }
            }
        }
}

extern "C" void kernel_launch(void* const* d_in, const int* in_sizes, int n_in,
                              void* d_out, int out_size, void* d_ws, size_t ws_size,
                              hipStream_t stream) {
    const float* answer = (const float*)d_in[0];   // [640][768] f32
    const float* vocab  = (const float*)d_in[1];   // [30000][768] f32
    const float* W      = (const float*)d_in[2];   // [768][768] f32
    const float* bvec   = (const float*)d_in[3];   // [768] f32

    char* ws = (char*)d_ws;
    unsigned short* Wt_bf   = (unsigned short*)ws;                      // 1,179,648 B
    unsigned short* A2_bf   = (unsigned short*)(ws + 1179648);          //   983,040 B
    float*          cptr    = (float*)(ws + 1179648 + 983040);          //     2,560 B
    unsigned short* vocabbf = (unsigned short*)(ws + 2165248);          // 46,080,000 B

    // 1. Wt = W^T (bf16), c = answer @ b
    prep_small<<<304, 256, 0, stream>>>(W, answer, bvec, Wt_bf, cptr);

    // 2. A2 = answer @ Wt (60 blocks) ∥ vocab f32->bf16 (2813 blocks on idle CUs)
    gemm_a2<<<A2BLK + CVTBLK, 256, 0, stream>>>(answer, Wt_bf, A2_bf, vocab, vocabbf);

    // 3. out[m][v] = sum_k A2[m][k] * vocab_bf(v,k) + c[m]
    //    1200 blocks (25 idle), XCD-grouped swizzle, pure-DMA staging.
    gemm_big<<<1200, 256, 0, stream>>>(A2_bf, vocabbf, cptr, (float*)d_out);
}

// Round 3
// 222.019 us; speedup vs baseline: 1.1273x; 1.0009x over previous
//
#include <hip/hip_runtime.h>

#define KDIM 768
#define MANS 640      // L*B*T
#define VV   30000
#define NGRP 235      // ceil(30000/128)
#define NKS  (KDIM / 64)                   // 12 k-steps
#define VELEM (VV * KDIM)                  // 23,040,000 floats in vocab
#define CVTBLK ((VELEM + 8191) / 8192)     // 2813 conversion blocks
#define A2BLK  ((MANS / 64) * (KDIM / 128))  // 60 gemm blocks

typedef __attribute__((ext_vector_type(4)))  float  f32x4;
typedef __attribute__((ext_vector_type(16))) float  f32x16;
typedef __attribute__((ext_vector_type(8)))  __bf16 bf16x8;
typedef __attribute__((ext_vector_type(8)))  unsigned short ushort8;

// native f32->bf16 (RNE via v_cvt_pk_bf16_f32; compiler packs pairs — m240)
__device__ __forceinline__ unsigned short f2bf(float f) {
    union { __bf16 h; unsigned short u; } t;
    t.h = (__bf16)f;
    return t.u;
}

__device__ __forceinline__ ushort8 cvt8(f32x4 a, f32x4 b) {
    union { bf16x8 h; ushort8 u; } c;
    c.h[0] = (__bf16)a.x; c.h[1] = (__bf16)a.y;
    c.h[2] = (__bf16)a.z; c.h[3] = (__bf16)a.w;
    c.h[4] = (__bf16)b.x; c.h[5] = (__bf16)b.y;
    c.h[6] = (__bf16)b.z; c.h[7] = (__bf16)b.w;
    return c.u;
}

__device__ __forceinline__ void load_lds16(const unsigned short* g, unsigned short* l) {
    __builtin_amdgcn_global_load_lds(
        (__attribute__((address_space(1))) void*)(void*)g,
        (__attribute__((address_space(3))) void*)l,
        16, 0, 0);
}

// A2F fragment layout (written by gemm_a2, read by gemm_big):
//   element (m, n):  mb=m>>7, wm=(m>>6)&1, fm=(m>>5)&1, colm=m&31
//                    kt=n>>6, g=(n>>4)&3, halfb=(n>>3)&1, e=n&7
//   off = ((((mb*12+kt)*2+wm)*2+fm)*4+g)*512 + (halfb*32+colm)*8 + e
// gemm_big wave-load: lane l reads 8 ushorts at off(...,l) -> coalesced 1 KB.
__device__ __forceinline__ long a2f_off(int m, int n) {
    int mb = m >> 7, wm = (m >> 6) & 1, fm = (m >> 5) & 1, colm = m & 31;
    int kt = n >> 6, g = (n >> 4) & 3, halfb = (n >> 3) & 1, e = n & 7;
    return ((((long)(mb * 12 + kt) * 2 + wm) * 2 + fm) * 4 + g) * 512
         + (halfb * 32 + colm) * 8 + e;
}

// ===================== prep_small =====================
// blocks [0,144):   W[768][768] f32 -> Wt[k][d]=W[d][k] bf16 (64x64 tiles)
// blocks [144,304): c[m] = dot(answer[m], b)
__global__ __launch_bounds__(256) void prep_small(
    const float* __restrict__ W, const float* __restrict__ A,
    const float* __restrict__ b, unsigned short* __restrict__ Wt_bf,
    float* __restrict__ cvec)
{
    __shared__ float ts[64][65];
    const int blk = blockIdx.x;
    if (blk < 144) {
        int bx = (blk % 12) * 64, by = (blk / 12) * 64;
        int tx = threadIdx.x & 63, tg = threadIdx.x >> 6;
#pragma unroll
        for (int i = 0; i < 16; ++i) {
            int r = tg * 16 + i;
            ts[r][tx] = W[(long)(by + r) * KDIM + bx + tx];
        }
        __syncthreads();
#pragma unroll
        for (int i = 0; i < 16; ++i) {
            int r = tg * 16 + i;
            Wt_bf[(long)(bx + r) * KDIM + by + tx] = f2bf(ts[tx][r]);
        }
    } else {
        int row  = (blk - 144) * 4 + (threadIdx.x >> 6);
        int lane = threadIdx.x & 63;
        const float* ap = A + (long)row * KDIM;
        float s = 0.f;
#pragma unroll
        for (int i = 0; i < KDIM / 64; ++i) s += ap[i * 64 + lane] * b[i * 64 + lane];
#pragma unroll
        for (int off = 32; off; off >>= 1) s += __shfl_down(s, off, 64);
        if (lane == 0) cvec[row] = s;
    }
}

// ===================== a2 gemm + vocab cvt (fused grid) =====================
// blocks [0,60):      A2F[frag-order] = answer @ W  (bf16), single-buffer LDS.
// blocks [60,2873):   vocab f32 -> bf16 streaming cvt on the ~196 idle CUs.
__global__ __launch_bounds__(256) void gemm_a2(
    const float* __restrict__ Af, const unsigned short* __restrict__ Bp,
    unsigned short* __restrict__ outp,
    const float* __restrict__ vocab, unsigned short* __restrict__ vocab_bf)
{
    if (blockIdx.x >= A2BLK) {
        const long base = (long)(blockIdx.x - A2BLK) * 8192 + (long)threadIdx.x * 8;
#pragma unroll
        for (int p = 0; p < 4; ++p) {
            long idx = base + p * 2048;
            if (idx < VELEM) {
                f32x4 v0 = ((const f32x4*)(vocab + idx))[0];
                f32x4 v1 = ((const f32x4*)(vocab + idx))[1];
                *(ushort8*)(vocab_bf + idx) = cvt8(v0, v1);
            }
        }
        return;
    }

    constexpr int TM = 64, TN = 128;
    __shared__ unsigned short sA[TM * 64];   // 8 KB
    __shared__ unsigned short sB[TN * 64];   // 16 KB

    const int t    = threadIdx.x;
    const int lane = t & 63;
    const int w    = t >> 6;
    const int wm   = w >> 1;
    const int wn   = w & 1;
    const int half = lane >> 5;
    const int col  = lane & 31;
    const long m0  = (long)(blockIdx.x % (MANS / 64)) * TM;
    const long n0  = (long)(blockIdx.x / (MANS / 64)) * TN;

    f32x16 acc[2];
    acc[0] = (f32x16)(0.f);
    acc[1] = (f32x16)(0.f);

    // A reg-stage addressing: 512 16B chunks, 2 per thread
    const float* gaf[2]; int laOff[2];
#pragma unroll
    for (int j = 0; j < 2; ++j) {
        int s   = (j * 4 + w) * 64 + lane;
        int row = s >> 3;
        int c   = (s & 7) ^ (row & 7);
        gaf[j]   = Af + (m0 + row) * KDIM + c * 8;
        laOff[j] = s * 8;
    }
    // B DMA addressing: 1024 chunks, source XOR-swizzled, dest wave-uniform
    const unsigned short* gb[4]; unsigned short* lbB[4];
#pragma unroll
    for (int j = 0; j < 4; ++j) {
        int s   = (j * 4 + w) * 64 + lane;
        int row = s >> 3;
        int c   = (s & 7) ^ (row & 7);
        gb[j]  = Bp + (n0 + row) * KDIM + c * 8;
        lbB[j] = &sB[(j * 4 + w) * 64 * 8];
    }

    for (int k0 = 0; k0 < KDIM; k0 += 64) {
#pragma unroll
        for (int j = 0; j < 4; ++j) load_lds16(gb[j] + k0, lbB[j]);
#pragma unroll
        for (int j = 0; j < 2; ++j) {
            f32x4 v0 = ((const f32x4*)(gaf[j] + k0))[0];
            f32x4 v1 = ((const f32x4*)(gaf[j] + k0))[1];
            *(ushort8*)(&sA[0] + laOff[j]) = cvt8(v0, v1);
        }
        __syncthreads();

#pragma unroll
        for (int g = 0; g < 4; ++g) {
            const int cg = g * 2 + half;
            int arow = wm * 32 + col;
            bf16x8 af = *(const bf16x8*)&sA[(arow * 8 + (cg ^ (arow & 7))) * 8];
#pragma unroll
            for (int fn = 0; fn < 2; ++fn) {
                int brow = wn * 64 + fn * 32 + col;
                bf16x8 bfv = *(const bf16x8*)&sB[(brow * 8 + (cg ^ (brow & 7))) * 8];
                acc[fn] = __builtin_amdgcn_mfma_f32_32x32x16_bf16(
                    af, bfv, acc[fn], 0, 0, 0);
            }
        }
        __syncthreads();
    }

    // epilogue: scatter into A2F fragment layout (same store count as before)
#pragma unroll
    for (int fn = 0; fn < 2; ++fn) {
        int n = (int)n0 + wn * 64 + fn * 32 + col;
#pragma unroll
        for (int rg = 0; rg < 16; ++rg) {
            int m = (int)m0 + wm * 32 + (rg & 3) + 8 * (rg >> 2) + 4 * half;
            outp[a2f_off(m, n)] = f2bf(acc[fn][rg]);
        }
    }
}

// ===================== big gemm: out = A2F @ vocab_bf^T + c =====================
// 128x128 tile, BK=64. A operands read directly from L2 (A2F fragment layout,
// 983 KB — L2-resident per XCD); B double-buffered in 2x16 KB LDS via DMA.
// T3-minimum schedule: STAGE(t+1) -> compute(t) -> vmcnt(0) -> s_barrier.
// One barrier per k-step; loads fly across the whole MFMA phase (no issue-drain).
// LDS stays 32 KB -> 5 blocks/CU co-residency preserved (round-1 lesson).
__global__ __launch_bounds__(256) void gemm_big(
    const unsigned short* __restrict__ A, const unsigned short* __restrict__ Bbf,
    const float* __restrict__ cvec, float* __restrict__ outp)
{
    const int id    = blockIdx.x;
    const int x     = id & 7;
    const int q     = id >> 3;
    const int m_idx = q % 5;
    const int n_grp = (q / 5) * 8 + x;
    if (n_grp >= NGRP) return;               // 25 pad blocks idle

    __shared__ unsigned short sB[2][128 * 64];   // 2 x 16 KB

    const int t    = threadIdx.x;
    const int lane = t & 63;
    const int w    = t >> 6;
    const int wm   = w >> 1;
    const int wn   = w & 1;
    const int half = lane >> 5;
    const int col  = lane & 31;
    const long n0  = (long)n_grp * 128;

    f32x16 acc[2][2];
#pragma unroll
    for (int i = 0; i < 2; ++i)
#pragma unroll
        for (int j = 0; j < 2; ++j) acc[i][j] = (f32x16)(0.f);

    // A fragment pointers: wave-coalesced 1 KB loads from L2-resident A2F.
    // off(kt,fm,g) = ((((m_idx*12+kt)*2+wm)*2+fm)*4+g)*512 + lane*8
    const unsigned short* aBase = A + (((long)(m_idx * 12) * 2 + wm) * 2) * 4 * 512
                                    + lane * 8;
    // per kt stride: 2*2*4*512 = 8192 ushorts; fm stride 4*512=2048; g stride 512.

    // B staging: 1024 chunks via DMA, source XOR-swizzled, dest wave-uniform
    const unsigned short* gb[4];
    int lbOff[4];
#pragma unroll
    for (int j = 0; j < 4; ++j) {
        int s   = (j * 4 + w) * 64 + lane;
        int row = s >> 3;
        int c   = (s & 7) ^ (row & 7);
        long grow = n0 + row;
        if (grow > VV - 1) grow = VV - 1;
        gb[j]    = Bbf + grow * KDIM + c * 8;
        lbOff[j] = (j * 4 + w) * 64 * 8;     // wave-uniform chunk base in one buffer
    }

    auto stage = [&](int kt, int buf) {
        const int o = buf * (128 * 64);
#pragma unroll
        for (int j = 0; j < 4; ++j)
            load_lds16(gb[j] + kt * 64, &sB[0][0] + o + lbOff[j]);
    };

    auto compute = [&](int kt, int buf) {
        const unsigned short* bB = &sB[0][0] + buf * (128 * 64);
        const unsigned short* aK = aBase + (long)kt * 8192;
#pragma unroll
        for (int g = 0; g < 4; ++g) {
            const int cg = g * 2 + half;
            bf16x8 af[2], bfr[2];
#pragma unroll
            for (int fm = 0; fm < 2; ++fm)
                af[fm] = *(const bf16x8*)(aK + fm * 2048 + g * 512);
#pragma unroll
            for (int fn = 0; fn < 2; ++fn) {
                int row = wn * 64 + fn * 32 + col;
                bfr[fn] = *(const bf16x8*)&bB[(row * 8 + (cg ^ (row & 7))) * 8];
            }
#pragma unroll
            for (int fm = 0; fm < 2; ++fm)
#pragma unroll
                for (int fn = 0; fn < 2; ++fn)
                    acc[fm][fn] = __builtin_amdgcn_mfma_f32_32x32x16_bf16(
                        af[fm], bfr[fn], acc[fm][fn], 0, 0, 0);
        }
    };

    // prologue: stage kt=0 into buf 0, drain, barrier
    stage(0, 0);
    asm volatile("s_waitcnt vmcnt(0)" ::: "memory");
    __builtin_amdgcn_s_barrier();

    int p = 0;
    for (int kt = 0; kt < NKS - 1; ++kt) {
        stage(kt + 1, p ^ 1);                 // issue next-tile DMA EARLY
        compute(kt, p);                       // loads fly under 16 MFMAs
        asm volatile("s_waitcnt vmcnt(0)" ::: "memory");
        __builtin_amdgcn_s_barrier();         // single barrier per k-step
        p ^= 1;
    }
    compute(NKS - 1, p);                      // epilogue tile, no stage

    const long m0 = (long)m_idx * 128;
#pragma unroll
    for (int fm = 0; fm < 2; ++fm)
#pragma unroll
        for (int fn = 0; fn < 2; ++fn) {
            long n = n0 + wn * 64 + fn * 32 + col;
            if (n < VV) {
#pragma unroll
                for (int rg = 0; rg < 16; ++rg) {
                    long m = m0 + wm * 64 + fm * 32
                           + (rg & 3) + 8 * (rg >> 2) + 4 * half;
                    outp[m * (long)VV + n] = acc[fm][fn][rg] + cvec[m];
                }
            }
        }
}

extern "C" void kernel_launch(void* const* d_in, const int* in_sizes, int n_in,
                              void* d_out, int out_size, void* d_ws, size_t ws_size,
                              hipStream_t stream) {
    const float* answer = (const float*)d_in[0];   // [640][768] f32
    const float* vocab  = (const float*)d_in[1];   // [30000][768] f32
    const float* W      = (const float*)d_in[2];   // [768][768] f32
    const float* bvec   = (const float*)d_in[3];   // [768] f32

    char* ws = (char*)d_ws;
    unsigned short* Wt_bf   = (unsigned short*)ws;                      // 1,179,648 B
    unsigned short* A2F     = (unsigned short*)(ws + 1179648);          //   983,040 B
    float*          cptr    = (float*)(ws + 1179648 + 983040);          //     2,560 B
    unsigned short* vocabbf = (unsigned short*)(ws + 2165248);          // 46,080,000 B

    // 1. Wt = W^T (bf16), c = answer @ b
    prep_small<<<304, 256, 0, stream>>>(W, answer, bvec, Wt_bf, cptr);

    // 2. A2F = answer @ W in fragment order (60 blocks) ∥ vocab f32->bf16 (2813)
    gemm_a2<<<A2BLK + CVTBLK, 256, 0, stream>>>(answer, Wt_bf, A2F, vocab, vocabbf);

    // 3. out[m][v] = sum_k A2F[m][k] * vocab_bf(v,k) + c[m]
    //    1200 blocks (25 idle), XCD-grouped swizzle, B-only LDS pipeline.
    gemm_big<<<1200, 256, 0, stream>>>(A2F, vocabbf, cptr, (float*)d_out);
}

// Round 5
// 221.597 us; speedup vs baseline: 1.1295x; 1.0019x over previous
//
#include <hip/hip_runtime.h>

#define KDIM 768
#define MANS 640      // L*B*T
#define VV   30000
#define NGRP 235      // ceil(30000/128)
#define NKS  (KDIM / 64)                   // 12 k-steps
#define VELEM (VV * KDIM)                  // 23,040,000 floats in vocab
#define CVTBLK ((VELEM + 8191) / 8192)     // 2813 conversion blocks
#define A2BLK  ((MANS / 64) * (KDIM / 128))  // 60 gemm blocks

typedef __attribute__((ext_vector_type(4)))  float  f32x4;
typedef __attribute__((ext_vector_type(16))) float  f32x16;
typedef __attribute__((ext_vector_type(8)))  __bf16 bf16x8;
typedef __attribute__((ext_vector_type(8)))  unsigned short ushort8;

// native f32->bf16 (RNE via v_cvt_pk_bf16_f32; compiler packs pairs — m240)
__device__ __forceinline__ unsigned short f2bf(float f) {
    union { __bf16 h; unsigned short u; } t;
    t.h = (__bf16)f;
    return t.u;
}

__device__ __forceinline__ ushort8 cvt8(f32x4 a, f32x4 b) {
    union { bf16x8 h; ushort8 u; } c;
    c.h[0] = (__bf16)a.x; c.h[1] = (__bf16)a.y;
    c.h[2] = (__bf16)a.z; c.h[3] = (__bf16)a.w;
    c.h[4] = (__bf16)b.x; c.h[5] = (__bf16)b.y;
    c.h[6] = (__bf16)b.z; c.h[7] = (__bf16)b.w;
    return c.u;
}

__device__ __forceinline__ void load_lds16(const unsigned short* g, unsigned short* l) {
    __builtin_amdgcn_global_load_lds(
        (__attribute__((address_space(1))) void*)(void*)g,
        (__attribute__((address_space(3))) void*)l,
        16, 0, 0);
}

// A2F fragment layout (written by gemm_a2, read by gemm_big):
//   element (m, n):  mb=m>>7, wm=(m>>6)&1, fm=(m>>5)&1, colm=m&31
//                    kt=n>>6, g=(n>>4)&3, halfb=(n>>3)&1, e=n&7
//   off = ((((mb*12+kt)*2+wm)*2+fm)*4+g)*512 + (halfb*32+colm)*8 + e
// gemm_big wave-load: lane l reads 8 ushorts at off(...,l) -> coalesced 1 KB.
__device__ __forceinline__ long a2f_off(int m, int n) {
    int mb = m >> 7, wm = (m >> 6) & 1, fm = (m >> 5) & 1, colm = m & 31;
    int kt = n >> 6, g = (n >> 4) & 3, halfb = (n >> 3) & 1, e = n & 7;
    return ((((long)(mb * 12 + kt) * 2 + wm) * 2 + fm) * 4 + g) * 512
         + (halfb * 32 + colm) * 8 + e;
}

// ===================== prep_small =====================
// blocks [0,144):   W[768][768] f32 -> Wt[k][d]=W[d][k] bf16 (64x64 tiles)
// blocks [144,304): c[m] = dot(answer[m], b)
__global__ __launch_bounds__(256) void prep_small(
    const float* __restrict__ W, const float* __restrict__ A,
    const float* __restrict__ b, unsigned short* __restrict__ Wt_bf,
    float* __restrict__ cvec)
{
    __shared__ float ts[64][65];
    const int blk = blockIdx.x;
    if (blk < 144) {
        int bx = (blk % 12) * 64, by = (blk / 12) * 64;
        int tx = threadIdx.x & 63, tg = threadIdx.x >> 6;
#pragma unroll
        for (int i = 0; i < 16; ++i) {
            int r = tg * 16 + i;
            ts[r][tx] = W[(long)(by + r) * KDIM + bx + tx];
        }
        __syncthreads();
#pragma unroll
        for (int i = 0; i < 16; ++i) {
            int r = tg * 16 + i;
            Wt_bf[(long)(bx + r) * KDIM + by + tx] = f2bf(ts[tx][r]);
        }
    } else {
        int row  = (blk - 144) * 4 + (threadIdx.x >> 6);
        int lane = threadIdx.x & 63;
        const float* ap = A + (long)row * KDIM;
        float s = 0.f;
#pragma unroll
        for (int i = 0; i < KDIM / 64; ++i) s += ap[i * 64 + lane] * b[i * 64 + lane];
#pragma unroll
        for (int off = 32; off; off >>= 1) s += __shfl_down(s, off, 64);
        if (lane == 0) cvec[row] = s;
    }
}

// ===================== a2 gemm + vocab cvt (fused grid) =====================
// blocks [0,60):      A2F[frag-order] = answer @ W  (bf16), single-buffer LDS.
// blocks [60,2873):   vocab f32 -> bf16 streaming cvt on the ~196 idle CUs.
__global__ __launch_bounds__(256) void gemm_a2(
    const float* __restrict__ Af, const unsigned short* __restrict__ Bp,
    unsigned short* __restrict__ outp,
    const float* __restrict__ vocab, unsigned short* __restrict__ vocab_bf)
{
    if (blockIdx.x >= A2BLK) {
        const long base = (long)(blockIdx.x - A2BLK) * 8192 + (long)threadIdx.x * 8;
#pragma unroll
        for (int p = 0; p < 4; ++p) {
            long idx = base + p * 2048;
            if (idx < VELEM) {
                f32x4 v0 = ((const f32x4*)(vocab + idx))[0];
                f32x4 v1 = ((const f32x4*)(vocab + idx))[1];
                *(ushort8*)(vocab_bf + idx) = cvt8(v0, v1);
            }
        }
        return;
    }

    constexpr int TM = 64, TN = 128;
    __shared__ unsigned short sA[TM * 64];   // 8 KB
    __shared__ unsigned short sB[TN * 64];   // 16 KB

    const int t    = threadIdx.x;
    const int lane = t & 63;
    const int w    = t >> 6;
    const int wm   = w >> 1;
    const int wn   = w & 1;
    const int half = lane >> 5;
    const int col  = lane & 31;
    const long m0  = (long)(blockIdx.x % (MANS / 64)) * TM;
    const long n0  = (long)(blockIdx.x / (MANS / 64)) * TN;

    f32x16 acc[2];
    acc[0] = (f32x16)(0.f);
    acc[1] = (f32x16)(0.f);

    // A reg-stage addressing: 512 16B chunks, 2 per thread
    const float* gaf[2]; int laOff[2];
#pragma unroll
    for (int j = 0; j < 2; ++j) {
        int s   = (j * 4 + w) * 64 + lane;
        int row = s >> 3;
        int c   = (s & 7) ^ (row & 7);
        gaf[j]   = Af + (m0 + row) * KDIM + c * 8;
        laOff[j] = s * 8;
    }
    // B DMA addressing: 1024 chunks, source XOR-swizzled, dest wave-uniform
    const unsigned short* gb[4]; unsigned short* lbB[4];
#pragma unroll
    for (int j = 0; j < 4; ++j) {
        int s   = (j * 4 + w) * 64 + lane;
        int row = s >> 3;
        int c   = (s & 7) ^ (row & 7);
        gb[j]  = Bp + (n0 + row) * KDIM + c * 8;
        lbB[j] = &sB[(j * 4 + w) * 64 * 8];
    }

    for (int k0 = 0; k0 < KDIM; k0 += 64) {
#pragma unroll
        for (int j = 0; j < 4; ++j) load_lds16(gb[j] + k0, lbB[j]);
#pragma unroll
        for (int j = 0; j < 2; ++j) {
            f32x4 v0 = ((const f32x4*)(gaf[j] + k0))[0];
            f32x4 v1 = ((const f32x4*)(gaf[j] + k0))[1];
            *(ushort8*)(&sA[0] + laOff[j]) = cvt8(v0, v1);
        }
        __syncthreads();

#pragma unroll
        for (int g = 0; g < 4; ++g) {
            const int cg = g * 2 + half;
            int arow = wm * 32 + col;
            bf16x8 af = *(const bf16x8*)&sA[(arow * 8 + (cg ^ (arow & 7))) * 8];
#pragma unroll
            for (int fn = 0; fn < 2; ++fn) {
                int brow = wn * 64 + fn * 32 + col;
                bf16x8 bfv = *(const bf16x8*)&sB[(brow * 8 + (cg ^ (brow & 7))) * 8];
                acc[fn] = __builtin_amdgcn_mfma_f32_32x32x16_bf16(
                    af, bfv, acc[fn], 0, 0, 0);
            }
        }
        __syncthreads();
    }

    // epilogue: scatter into A2F fragment layout
#pragma unroll
    for (int fn = 0; fn < 2; ++fn) {
        int n = (int)n0 + wn * 64 + fn * 32 + col;
#pragma unroll
        for (int rg = 0; rg < 16; ++rg) {
            int m = (int)m0 + wm * 32 + (rg & 3) + 8 * (rg >> 2) + 4 * half;
            outp[a2f_off(m, n)] = f2bf(acc[fn][rg]);
        }
    }
}

// ===================== big gemm: out = A2F @ vocab_bf^T + c =====================
// 128x128 tile, BK=64. A from L2 (fragment order); B dbuf 2x16 KB LDS via DMA.
// T4 counted-wait schedule: per k-step, issue A-frag loads FIRST (oldest in the
// in-order vmcnt queue), then B-DMAs for kt+1 (newest). The compiler's wait to
// consume A is then a COUNTED vmcnt(8), leaving B in flight under the whole
// MFMA phase; vmcnt(0)+s_barrier once per k-step at the end (round-3 bug: A
// issued after B made every A-wait drain the B prefetch).
__global__ __launch_bounds__(256, 4) void gemm_big(
    const unsigned short* __restrict__ A, const unsigned short* __restrict__ Bbf,
    const float* __restrict__ cvec, float* __restrict__ outp)
{
    const int id    = blockIdx.x;
    const int x     = id & 7;
    const int q     = id >> 3;
    const int m_idx = q % 5;
    const int n_grp = (q / 5) * 8 + x;
    if (n_grp >= NGRP) return;               // 25 pad blocks idle

    __shared__ unsigned short sB[2][128 * 64];   // 2 x 16 KB

    const int t    = threadIdx.x;
    const int lane = t & 63;
    const int w    = t >> 6;
    const int wm   = w >> 1;
    const int wn   = w & 1;
    const int half = lane >> 5;
    const int col  = lane & 31;
    const long n0  = (long)n_grp * 128;

    f32x16 acc[2][2];
#pragma unroll
    for (int i = 0; i < 2; ++i)
#pragma unroll
        for (int j = 0; j < 2; ++j) acc[i][j] = (f32x16)(0.f);

    // A fragment base: wave-coalesced 1 KB loads from L2-resident A2F.
    const unsigned short* aBase = A + (((long)(m_idx * 12) * 2 + wm) * 2) * 4 * 512
                                    + lane * 8;
    // strides: kt 8192, fm 2048, g 512 (ushorts)

    // B staging: 1024 chunks via DMA, source XOR-swizzled, dest wave-uniform
    const unsigned short* gb[4];
    int lbOff[4];
#pragma unroll
    for (int j = 0; j < 4; ++j) {
        int s   = (j * 4 + w) * 64 + lane;
        int row = s >> 3;
        int c   = (s & 7) ^ (row & 7);
        long grow = n0 + row;
        if (grow > VV - 1) grow = VV - 1;
        gb[j]    = Bbf + grow * KDIM + c * 8;
        lbOff[j] = (j * 4 + w) * 64 * 8;
    }

    // prologue: stage kt=0 into buf 0, drain, barrier
#pragma unroll
    for (int j = 0; j < 4; ++j) load_lds16(gb[j], &sB[0][0] + lbOff[j]);
    asm volatile("s_waitcnt vmcnt(0)" ::: "memory");
    __builtin_amdgcn_s_barrier();

    for (int kt = 0; kt < NKS; ++kt) {
        const int p = kt & 1;
        // (1) A-frag loads for THIS k-step — oldest entries in vmem queue
        const unsigned short* aK = aBase + (long)kt * 8192;
        bf16x8 af[2][4];
#pragma unroll
        for (int fm = 0; fm < 2; ++fm)
#pragma unroll
            for (int g = 0; g < 4; ++g)
                af[fm][g] = *(const bf16x8*)(aK + fm * 2048 + g * 512);
        __builtin_amdgcn_sched_barrier(0);
        // (2) B-DMA for NEXT k-step — newest; flies under the MFMA phase
        if (kt < NKS - 1) {
#pragma unroll
            for (int j = 0; j < 4; ++j)
                load_lds16(gb[j] + (kt + 1) * 64,
                           &sB[0][0] + (p ^ 1) * (128 * 64) + lbOff[j]);
        }
        __builtin_amdgcn_sched_barrier(0);
        // (3) MFMA phase: counted wait on A (vmcnt(8)); B(kt) via ds_read
        const unsigned short* bB = &sB[0][0] + p * (128 * 64);
#pragma unroll
        for (int g = 0; g < 4; ++g) {
            const int cg = g * 2 + half;
            bf16x8 bfr[2];
#pragma unroll
            for (int fn = 0; fn < 2; ++fn) {
                int row = wn * 64 + fn * 32 + col;
                bfr[fn] = *(const bf16x8*)&bB[(row * 8 + (cg ^ (row & 7))) * 8];
            }
#pragma unroll
            for (int fm = 0; fm < 2; ++fm)
#pragma unroll
                for (int fn = 0; fn < 2; ++fn)
                    acc[fm][fn] = __builtin_amdgcn_mfma_f32_32x32x16_bf16(
                        af[fm][g], bfr[fn], acc[fm][fn], 0, 0, 0);
        }
        // (4) one drain + barrier per k-step
        if (kt < NKS - 1) {
            asm volatile("s_waitcnt vmcnt(0)" ::: "memory");
            __builtin_amdgcn_s_barrier();
        }
    }

    const long m0 = (long)m_idx * 128;
#pragma unroll
    for (int fm = 0; fm < 2; ++fm)
#pragma unroll
        for (int fn = 0; fn < 2; ++fn) {
            long n = n0 + wn * 64 + fn * 32 + col;
            if (n < VV) {
#pragma unroll
                for (int rg = 0; rg < 16; ++rg) {
                    long m = m0 + wm * 64 + fm * 32
                           + (rg & 3) + 8 * (rg >> 2) + 4 * half;
                    outp[m * (long)VV + n] = acc[fm][fn][rg] + cvec[m];
                }
            }
        }
}

extern "C" void kernel_launch(void* const* d_in, const int* in_sizes, int n_in,
                              void* d_out, int out_size, void* d_ws, size_t ws_size,
                              hipStream_t stream) {
    const float* answer = (const float*)d_in[0];   // [640][768] f32
    const float* vocab  = (const float*)d_in[1];   // [30000][768] f32
    const float* W      = (const float*)d_in[2];   // [768][768] f32
    const float* bvec   = (const float*)d_in[3];   // [768] f32

    char* ws = (char*)d_ws;
    unsigned short* Wt_bf   = (unsigned short*)ws;                      // 1,179,648 B
    unsigned short* A2F     = (unsigned short*)(ws + 1179648);          //   983,040 B
    float*          cptr    = (float*)(ws + 1179648 + 983040);          //     2,560 B
    unsigned short* vocabbf = (unsigned short*)(ws + 2165248);          // 46,080,000 B

    // 1. Wt = W^T (bf16), c = answer @ b
    prep_small<<<304, 256, 0, stream>>>(W, answer, bvec, Wt_bf, cptr);

    // 2. A2F = answer @ W in fragment order (60 blocks) ∥ vocab f32->bf16 (2813)
    gemm_a2<<<A2BLK + CVTBLK, 256, 0, stream>>>(answer, Wt_bf, A2F, vocab, vocabbf);

    // 3. out[m][v] = sum_k A2F[m][k] * vocab_bf(v,k) + c[m]
    //    1200 blocks (25 idle), XCD-grouped swizzle, counted-vmcnt pipeline.
    gemm_big<<<1200, 256, 0, stream>>>(A2F, vocabbf, cptr, (float*)d_out);
}